// Round 4
// baseline (134.368 us; speedup 1.0000x reference)
//
#include <hip/hip_runtime.h>
#include <hip/hip_cooperative_groups.h>
#include <math.h>

namespace cg = cooperative_groups;

#define HW   3136   // 56*56
#define NC   512    // channels
#define NB   32     // batch
#define KSEL 256    // top-k
#define NBLK 256    // 1 block/CU -> cooperative co-residency trivially satisfiable
#define NTHR 512    // 8 waves/block

typedef float f32x4 __attribute__((ext_vector_type(4)));

// ---------------------------------------------------------------------------
// Fused cooperative kernel: reduce -> sync -> topk -> sync -> gather.
// 256 blocks x 512 threads (1 block/CU). Phase 3 x-reads should hit Infinity
// Cache (x = 205.5 MB < 256 MB, fetched by phase 1); out stores non-temporal.
// ---------------------------------------------------------------------------
__global__ __launch_bounds__(NTHR, 2) void fused_attention(
    const float* __restrict__ x, const float* __restrict__ w,
    float* __restrict__ out, float* __restrict__ desc,
    int* __restrict__ sidx, float* __restrict__ sval)
{
    cg::grid_group grid = cg::this_grid();
    const int tid  = threadIdx.x;
    const int wid  = tid >> 6;
    const int lane = tid & 63;

    // ---- Phase 1: per-(b,c) mean+max over HW; desc = mean + max ----
    // conv(avg)+conv(mx) == conv(avg+mx) by linearity (no bias).
    {
        const int row0 = blockIdx.x * 64;          // 256 blocks * 64 rows = 16384
        for (int r = 0; r < 8; ++r) {
            const int row = row0 + wid * 8 + r;    // 8 waves * 8 rows each
            const f32x4* p = (const f32x4*)(x + (size_t)row * HW);
            float s = 0.0f, m = -INFINITY;
#pragma unroll
            for (int i = 0; i < 12; ++i) {         // 12*64 = 768 float4
                f32x4 v = p[lane + i * 64];
                s += (v.x + v.y) + (v.z + v.w);
                m = fmaxf(m, fmaxf(fmaxf(v.x, v.y), fmaxf(v.z, v.w)));
            }
            if (lane < 16) {                       // tail: 784-768
                f32x4 v = p[lane + 768];
                s += (v.x + v.y) + (v.z + v.w);
                m = fmaxf(m, fmaxf(fmaxf(v.x, v.y), fmaxf(v.z, v.w)));
            }
#pragma unroll
            for (int off = 32; off; off >>= 1) {
                s += __shfl_down(s, off, 64);
                m = fmaxf(m, __shfl_down(m, off, 64));
            }
            if (lane == 0) desc[row] = s * (1.0f / (float)HW) + m;
        }
    }

    grid.sync();

    // ---- Phase 2: blocks 0..31 -> conv1d + sigmoid + top-K select ----
    __shared__ float s_d[NC + 2];
    __shared__ float s_score[NC];
    __shared__ int   s_wcnt[8];
    if (blockIdx.x < NB) {
        const int b = blockIdx.x;
        const int c = tid;                          // 512 threads, one channel each
        if (c == 0) { s_d[0] = 0.0f; s_d[NC + 1] = 0.0f; }
        s_d[c + 1] = desc[b * NC + c];
        __syncthreads();

        const float w0 = w[0], w1 = w[1], w2 = w[2];
        // cross-correlation (lax conv does NOT flip the kernel)
        const float t = s_d[c] * w0 + s_d[c + 1] * w1 + s_d[c + 2] * w2;
        const float score = 1.0f / (1.0f + expf(-t));
        s_score[c] = score;
        __syncthreads();

        int rank = 0;
        for (int j = 0; j < NC; ++j) {
            const float sj = s_score[j];
            rank += (sj > score) || (sj == score && j < c);  // lax.top_k tie-break
        }
        const int flag = (rank < KSEL) ? 1 : 0;

        const unsigned long long bal = __ballot(flag);
        if (lane == 0) s_wcnt[wid] = __popcll(bal);
        __syncthreads();

        if (flag) {   // ascending-channel compaction == reference argsort re-sort
            int pos = __popcll(bal & ((1ULL << lane) - 1ULL));
            for (int wj = 0; wj < wid; ++wj) pos += s_wcnt[wj];
            sidx[b * KSEL + pos] = c;
            sval[b * KSEL + pos] = score;
        }
    }

    grid.sync();

    // ---- Phase 3: gather selected channels, scale, NT-store ----
    {
        const int t = tid;
        for (int p = 0; p < 32; ++p) {             // 256 blocks * 32 = 8192 pairs
            const int bk = blockIdx.x * 32 + p;
            const int b  = bk >> 8;                // KSEL == 256
            const int ch = sidx[bk];
            const float sv = sval[bk];

            const f32x4* src = (const f32x4*)(x + ((size_t)b * NC + ch) * HW);
            f32x4*       dst = (f32x4*)(out + (size_t)bk * HW);

            f32x4 v = src[t];                      // 784 = 512 + 272
            v.x *= sv; v.y *= sv; v.z *= sv; v.w *= sv;
            __builtin_nontemporal_store(v, &dst[t]);
            if (t < 272) {
                f32x4 u = src[512 + t];
                u.x *= sv; u.y *= sv; u.z *= sv; u.w *= sv;
                __builtin_nontemporal_store(u, &dst[512 + t]);
            }
        }
    }
}

// ---------------------------------------------------------------------------
// Fallback path (proven round-2 kernels) if cooperative launch is rejected.
// ---------------------------------------------------------------------------
__global__ __launch_bounds__(256) void reduce_mean_max(
    const float* __restrict__ x, float* __restrict__ desc)
{
    const int gwave = (blockIdx.x * blockDim.x + threadIdx.x) >> 6;
    const int lane  = threadIdx.x & 63;
    const f32x4* p = (const f32x4*)(x + (size_t)gwave * HW);
    float s = 0.0f, m = -INFINITY;
#pragma unroll
    for (int i = 0; i < 12; ++i) {
        f32x4 v = p[lane + i * 64];
        s += (v.x + v.y) + (v.z + v.w);
        m = fmaxf(m, fmaxf(fmaxf(v.x, v.y), fmaxf(v.z, v.w)));
    }
    if (lane < 16) {
        f32x4 v = p[lane + 768];
        s += (v.x + v.y) + (v.z + v.w);
        m = fmaxf(m, fmaxf(fmaxf(v.x, v.y), fmaxf(v.z, v.w)));
    }
#pragma unroll
    for (int off = 32; off; off >>= 1) {
        s += __shfl_down(s, off, 64);
        m = fmaxf(m, __shfl_down(m, off, 64));
    }
    if (lane == 0) desc[gwave] = s * (1.0f / (float)HW) + m;
}

__global__ __launch_bounds__(512) void score_topk(
    const float* __restrict__ desc, const float* __restrict__ w,
    int* __restrict__ sidx, float* __restrict__ sval)
{
    const int b = blockIdx.x;
    const int c = threadIdx.x;
    __shared__ float s_d[NC + 2];
    __shared__ float s_score[NC];
    __shared__ int   s_wcnt[8];
    if (c == 0) { s_d[0] = 0.0f; s_d[NC + 1] = 0.0f; }
    s_d[c + 1] = desc[b * NC + c];
    __syncthreads();
    const float w0 = w[0], w1 = w[1], w2 = w[2];
    const float t = s_d[c] * w0 + s_d[c + 1] * w1 + s_d[c + 2] * w2;
    const float score = 1.0f / (1.0f + expf(-t));
    s_score[c] = score;
    __syncthreads();
    int rank = 0;
    for (int j = 0; j < NC; ++j) {
        const float sj = s_score[j];
        rank += (sj > score) || (sj == score && j < c);
    }
    const int flag = (rank < KSEL) ? 1 : 0;
    const unsigned long long bal = __ballot(flag);
    const int wid = c >> 6, lane = c & 63;
    if (lane == 0) s_wcnt[wid] = __popcll(bal);
    __syncthreads();
    if (flag) {
        int pos = __popcll(bal & ((1ULL << lane) - 1ULL));
        for (int wj = 0; wj < wid; ++wj) pos += s_wcnt[wj];
        sidx[b * KSEL + pos] = c;
        sval[b * KSEL + pos] = score;
    }
}

__global__ __launch_bounds__(256) void gather_scale(
    const float* __restrict__ x, const int* __restrict__ sidx,
    const float* __restrict__ sval, float* __restrict__ out)
{
    const int bk = blockIdx.x;
    const int b  = bk >> 8;
    const int ch = sidx[bk];
    const float sv = sval[bk];
    const f32x4* src = (const f32x4*)(x + ((size_t)b * NC + ch) * HW);
    f32x4*       dst = (f32x4*)(out + (size_t)bk * HW);
    const int t = threadIdx.x;
#pragma unroll
    for (int i = 0; i < 3; ++i) {
        f32x4 v = src[t + i * 256];
        v.x *= sv; v.y *= sv; v.z *= sv; v.w *= sv;
        __builtin_nontemporal_store(v, &dst[t + i * 256]);
    }
    if (t < 16) {
        f32x4 v = src[t + 768];
        v.x *= sv; v.y *= sv; v.z *= sv; v.w *= sv;
        __builtin_nontemporal_store(v, &dst[t + 768]);
    }
}

extern "C" void kernel_launch(void* const* d_in, const int* in_sizes, int n_in,
                              void* d_out, int out_size, void* d_ws, size_t ws_size,
                              hipStream_t stream)
{
    const float* x = (const float*)d_in[0];   // [32,512,56,56]
    const float* w = (const float*)d_in[1];   // [1,1,3] -> 3 floats
    float* out = (float*)d_out;               // [32,256,56,56]

    // workspace (floats): desc[16384] | sval[8192] | sidx[8192 ints]
    float* desc = (float*)d_ws;
    float* sval = desc + NB * NC;
    int*   sidx = (int*)(sval + NB * KSEL);

    void* args[] = { (void*)&x, (void*)&w, (void*)&out,
                     (void*)&desc, (void*)&sidx, (void*)&sval };
    hipError_t err = hipLaunchCooperativeKernel((const void*)fused_attention,
                                                dim3(NBLK), dim3(NTHR), args, 0, stream);
    if (err != hipSuccess) {
        // deterministic fallback: proven 3-kernel path
        reduce_mean_max<<<(NB * NC) / 4, 256, 0, stream>>>(x, desc);
        score_topk<<<NB, NC, 0, stream>>>(desc, w, sidx, sval);
        gather_scale<<<NB * KSEL, 256, 0, stream>>>(x, sidx, sval, out);
    }
}